// Round 1
// baseline (3187.461 us; speedup 1.0000x reference)
//
#include <hip/hip_runtime.h>
#include <hip/hip_bf16.h>

#define N_ 1024
#define M_ 1152
#define L_ 32
#define K2_ 2304            // fused contraction: [r, h] @ [W0, W1]^T
#define NATSTRIDE (L_*M_)   // 36864
#define CONVK 129
#define OUTW 1024

#define BM 128
#define BN 128
#define BK 64
#define LDP 72              // padded LDS k-stride (elems): 72*2B=144B -> bank-conflict-free

typedef __attribute__((ext_vector_type(8))) short short8;
typedef __attribute__((ext_vector_type(4))) float f32x4;

__device__ __forceinline__ unsigned short f2bf(float f) {
    unsigned int u = __float_as_uint(f);
    u += 0x7FFFu + ((u >> 16) & 1u);   // round-to-nearest-even
    return (unsigned short)(u >> 16);
}

// Build Wcat bf16 [M_][K2_]: Wcat[m][k] = k<M_ ? convW[m][k][0] : convW[m][k-M_][1]
__global__ __launch_bounds__(256) void build_wcat(const float* __restrict__ convW,
                                                  unsigned short* __restrict__ wcat) {
    int idx = blockIdx.x * blockDim.x + threadIdx.x;
    if (idx >= M_ * K2_) return;
    int m = idx / K2_;
    int k = idx - m * K2_;
    float v = (k < M_) ? convW[(size_t)m * K2_ + 2 * k]
                       : convW[(size_t)m * K2_ + 2 * (k - M_) + 1];
    wcat[idx] = f2bf(v);
}

// h0 = bf16(NATree[:, L-1, :])
__global__ __launch_bounds__(256) void build_h0(const float* __restrict__ nat,
                                                unsigned short* __restrict__ h0) {
    int idx = blockIdx.x * blockDim.x + threadIdx.x;
    if (idx >= N_ * M_) return;
    int n = idx / M_;
    int m = idx - n * M_;
    h0[idx] = f2bf(nat[(size_t)n * NATSTRIDE + (size_t)(L_ - 1) * M_ + m]);
}

// One recurrence step: C = r@W0^T + h@W1^T + b ; h_new = tanh(C) + r
// If final: res = tanh(tanh(h_new) + x) (fp32), else write bf16 h_new.
__global__ __launch_bounds__(256) void step_kernel(
    const float* __restrict__ natR,          // fp32 r rows, row stride NATSTRIDE
    const unsigned short* __restrict__ hIn,  // bf16 h, row stride M_
    const unsigned short* __restrict__ wcat, // bf16 [M_][K2_]
    const float* __restrict__ convb,
    const float* __restrict__ x,
    unsigned short* __restrict__ hOut,
    float* __restrict__ resOut,
    int final_step)
{
    __shared__ __align__(16) unsigned short As[BM * LDP];
    __shared__ __align__(16) unsigned short Bs[BN * LDP];

    int tid = threadIdx.x;
    int lane = tid & 63;
    int w = tid >> 6;
    int wr = w >> 1, wc = w & 1;       // 2x2 wave grid, 64x64 per wave
    int n0 = blockIdx.y * BM;
    int m0 = blockIdx.x * BN;
    int lr = lane & 15;                // fragment row (A: n) / col (B: m)
    int lk = (lane >> 4) * 8;          // fragment k base

    f32x4 acc[4][4] = {};

    for (int kb = 0; kb < K2_; kb += BK) {
        bool fromR = (kb < M_);
        int koff = fromR ? kb : (kb - M_);
        // ---- stage A (r fp32->bf16, or h bf16) : 128 rows x 64 k
        #pragma unroll
        for (int i = 0; i < 4; ++i) {
            int g = i * 256 + tid;
            int row = g >> 3;
            int kcol = (g & 7) * 8;
            short8 av;
            if (fromR) {
                const float* src = natR + (size_t)(n0 + row) * NATSTRIDE + koff + kcol;
                f32x4 v0 = *(const f32x4*)(src);
                f32x4 v1 = *(const f32x4*)(src + 4);
                #pragma unroll
                for (int e = 0; e < 4; ++e) {
                    av[e]     = (short)f2bf(v0[e]);
                    av[4 + e] = (short)f2bf(v1[e]);
                }
            } else {
                av = *(const short8*)(hIn + (size_t)(n0 + row) * M_ + koff + kcol);
            }
            *(short8*)&As[row * LDP + kcol] = av;
        }
        // ---- stage B (Wcat bf16) : 128 rows(m) x 64 k
        #pragma unroll
        for (int i = 0; i < 4; ++i) {
            int g = i * 256 + tid;
            int row = g >> 3;
            int kcol = (g & 7) * 8;
            short8 bv = *(const short8*)(wcat + (size_t)(m0 + row) * K2_ + kb + kcol);
            *(short8*)&Bs[row * LDP + kcol] = bv;
        }
        __syncthreads();
        // ---- MFMA over this K-tile
        #pragma unroll
        for (int ks = 0; ks < BK; ks += 32) {
            short8 a[4], b[4];
            #pragma unroll
            for (int mi = 0; mi < 4; ++mi)
                a[mi] = *(const short8*)&As[(wr * 64 + mi * 16 + lr) * LDP + ks + lk];
            #pragma unroll
            for (int ni = 0; ni < 4; ++ni)
                b[ni] = *(const short8*)&Bs[(wc * 64 + ni * 16 + lr) * LDP + ks + lk];
            #pragma unroll
            for (int mi = 0; mi < 4; ++mi)
                #pragma unroll
                for (int ni = 0; ni < 4; ++ni)
                    acc[mi][ni] = __builtin_amdgcn_mfma_f32_16x16x32_bf16(
                        a[mi], b[ni], acc[mi][ni], 0, 0, 0);
        }
        __syncthreads();
    }

    // ---- epilogue
    #pragma unroll
    for (int mi = 0; mi < 4; ++mi) {
        #pragma unroll
        for (int ni = 0; ni < 4; ++ni) {
            int mloc = m0 + wc * 64 + ni * 16 + lr;
            float bias = convb[mloc];
            #pragma unroll
            for (int j = 0; j < 4; ++j) {
                int nloc = n0 + wr * 64 + mi * 16 + (lane >> 4) * 4 + j;
                float c = acc[mi][ni][j] + bias;
                float hv = tanhf(c) + natR[(size_t)nloc * NATSTRIDE + mloc];
                if (final_step) {
                    float res = tanhf(tanhf(hv) + x[(size_t)nloc * M_ + mloc]);
                    resOut[(size_t)nloc * M_ + mloc] = res;
                } else {
                    hOut[(size_t)nloc * M_ + mloc] = f2bf(hv);
                }
            }
        }
    }
}

// out[n][j] = conv2b + sum_k res[n][j+k] * conv2W[k]
__global__ __launch_bounds__(256) void conv_out_kernel(
    const float* __restrict__ res, const float* __restrict__ w2,
    const float* __restrict__ b2, float* __restrict__ out)
{
    __shared__ float row[M_];
    __shared__ float wk[CONVK];
    int n = blockIdx.x;
    int tid = threadIdx.x;
    for (int i = tid; i < M_; i += 256) row[i] = res[(size_t)n * M_ + i];
    if (tid < CONVK) wk[tid] = w2[tid];
    __syncthreads();
    float b = b2[0];
    int j0 = tid * 4;
    float s0 = b, s1 = b, s2 = b, s3 = b;
    float r0 = row[j0], r1 = row[j0 + 1], r2 = row[j0 + 2], r3 = row[j0 + 3];
    for (int k = 0; k < CONVK; ++k) {
        float wv = wk[k];
        s0 += r0 * wv; s1 += r1 * wv; s2 += r2 * wv; s3 += r3 * wv;
        if (k < CONVK - 1) { r0 = r1; r1 = r2; r2 = r3; r3 = row[j0 + 4 + k]; }
    }
    float* o = out + (size_t)n * OUTW + j0;
    o[0] = s0; o[1] = s1; o[2] = s2; o[3] = s3;
}

extern "C" void kernel_launch(void* const* d_in, const int* in_sizes, int n_in,
                              void* d_out, int out_size, void* d_ws, size_t ws_size,
                              hipStream_t stream) {
    const float* NATree = (const float*)d_in[0];
    const float* x      = (const float*)d_in[1];
    const float* convW  = (const float*)d_in[2];
    const float* convb  = (const float*)d_in[3];
    const float* conv2W = (const float*)d_in[4];
    const float* conv2b = (const float*)d_in[5];
    float* out = (float*)d_out;

    char* ws = (char*)d_ws;
    size_t off = 0;
    unsigned short* wcat = (unsigned short*)(ws + off);
    off += (size_t)M_ * K2_ * 2;  off = (off + 255) & ~(size_t)255;
    unsigned short* hA = (unsigned short*)(ws + off);
    off += (size_t)N_ * M_ * 2;   off = (off + 255) & ~(size_t)255;
    unsigned short* hB = (unsigned short*)(ws + off);
    off += (size_t)N_ * M_ * 2;   off = (off + 255) & ~(size_t)255;
    float* res = (float*)(ws + off);

    build_wcat<<<(M_ * K2_ + 255) / 256, 256, 0, stream>>>(convW, wcat);
    build_h0<<<(N_ * M_ + 255) / 256, 256, 0, stream>>>(NATree, hA);

    const unsigned short* hin = hA;
    unsigned short* hout = hB;
    for (int t = 0; t < 31; ++t) {
        int lrow = 30 - t;                 // r_t = NATree[:, L-2-t, :]
        int fin = (t == 30) ? 1 : 0;
        step_kernel<<<dim3(9, 8), 256, 0, stream>>>(
            NATree + (size_t)lrow * M_, hin, wcat, convb, x, hout, res, fin);
        unsigned short* tmp = hout;
        hout = (unsigned short*)hin;
        hin = tmp;
    }

    conv_out_kernel<<<1024, 256, 0, stream>>>(res, conv2W, conv2b, out);
}

// Round 2
// 1225.498 us; speedup vs baseline: 2.6010x; 2.6010x over previous
//
#include <hip/hip_runtime.h>
#include <hip/hip_bf16.h>

#define N_ 1024
#define M_ 1152
#define L_ 32
#define K2_ 2304            // fused contraction: [r, h] @ [W0, W1]^T
#define NATSTRIDE (L_*M_)   // 36864
#define CONVK 129
#define OUTW 1024

#define BM 64
#define BN 64
#define BK 64
#define NT (K2_ / BK)       // 36 K-tiles
#define LDP 72              // padded LDS k-stride: 144B rows -> conflict-free b128

typedef __attribute__((ext_vector_type(8))) short short8;
typedef __attribute__((ext_vector_type(4))) float f32x4;

__device__ __forceinline__ unsigned short f2bf(float f) {
    unsigned int u = __float_as_uint(f);
    u += 0x7FFFu + ((u >> 16) & 1u);   // round-to-nearest-even
    return (unsigned short)(u >> 16);
}

// Build Wcat bf16 [M_][K2_]: Wcat[m][k] = k<M_ ? convW[m][k][0] : convW[m][k-M_][1]
__global__ __launch_bounds__(256) void build_wcat(const float* __restrict__ convW,
                                                  unsigned short* __restrict__ wcat) {
    int idx = blockIdx.x * blockDim.x + threadIdx.x;
    if (idx >= M_ * K2_) return;
    int m = idx / K2_;
    int k = idx - m * K2_;
    float v = (k < M_) ? convW[(size_t)m * K2_ + 2 * k]
                       : convW[(size_t)m * K2_ + 2 * (k - M_) + 1];
    wcat[idx] = f2bf(v);
}

// h0 = bf16(NATree[:, L-1, :])
__global__ __launch_bounds__(256) void build_h0(const float* __restrict__ nat,
                                                unsigned short* __restrict__ h0) {
    int idx = blockIdx.x * blockDim.x + threadIdx.x;
    if (idx >= N_ * M_) return;
    int n = idx / M_;
    int m = idx - n * M_;
    h0[idx] = f2bf(nat[(size_t)n * NATSTRIDE + (size_t)(L_ - 1) * M_ + m]);
}

// One recurrence step: C = r@W0^T + h@W1^T + b ; h_new = tanh(C) + r
// 64x64 tile, 4 waves (2x2 of 32x32), register-prefetch pipeline.
__global__ __launch_bounds__(256) void step_kernel(
    const float* __restrict__ natR,          // fp32 r rows, row stride NATSTRIDE
    const unsigned short* __restrict__ hIn,  // bf16 h, row stride M_
    const unsigned short* __restrict__ wcat, // bf16 [M_][K2_]
    const float* __restrict__ convb,
    const float* __restrict__ x,
    unsigned short* __restrict__ hOut,
    float* __restrict__ resOut,
    int final_step)
{
    __shared__ __align__(16) unsigned short As[BM * LDP];
    __shared__ __align__(16) unsigned short Bs[BN * LDP];

    int tid = threadIdx.x;
    int lane = tid & 63;
    int w = tid >> 6;
    int wr = w >> 1, wc = w & 1;       // 2x2 wave grid, 32x32 per wave
    // XCD-aware swizzle (288 blocks, 288 % 8 == 0 -> bijective)
    int bid = blockIdx.y * 18 + blockIdx.x;
    int swz = (bid & 7) * 36 + (bid >> 3);
    int bx = swz % 18, by = swz / 18;
    int n0 = by * BM;
    int m0 = bx * BN;
    int lr = lane & 15;                // fragment row (A: n) / col (B: m)
    int lk = (lane >> 4) * 8;          // fragment k base

    int srow = tid >> 3;               // staging row 0..31 (two slots: +0, +32)
    int skcol = (tid & 7) * 8;         // staging k col

    f32x4 acc[2][2] = {};

    auto loadTile = [&](int it, short8 a[2], short8 b[2]) {
        int kb = it * BK;
        bool fromR = (kb < M_);
        int koff = fromR ? kb : (kb - M_);
        #pragma unroll
        for (int i = 0; i < 2; ++i) {
            int row = srow + i * 32;
            if (fromR) {
                const float* s = natR + (size_t)(n0 + row) * NATSTRIDE + koff + skcol;
                f32x4 v0 = *(const f32x4*)(s);
                f32x4 v1 = *(const f32x4*)(s + 4);
                short8 t;
                #pragma unroll
                for (int e = 0; e < 4; ++e) {
                    t[e]     = (short)f2bf(v0[e]);
                    t[4 + e] = (short)f2bf(v1[e]);
                }
                a[i] = t;
            } else {
                a[i] = *(const short8*)(hIn + (size_t)(n0 + row) * M_ + koff + skcol);
            }
            b[i] = *(const short8*)(wcat + (size_t)(m0 + row) * K2_ + kb + skcol);
        }
    };
    auto writeTile = [&](short8 a[2], short8 b[2]) {
        #pragma unroll
        for (int i = 0; i < 2; ++i) {
            *(short8*)&As[(srow + i * 32) * LDP + skcol] = a[i];
            *(short8*)&Bs[(srow + i * 32) * LDP + skcol] = b[i];
        }
    };

    // prologue: stage tile 0
    {
        short8 a0[2], b0[2];
        loadTile(0, a0, b0);
        writeTile(a0, b0);
    }
    __syncthreads();

    for (int it = 0; it < NT; ++it) {
        short8 a2[2], b2[2];
        if (it + 1 < NT) loadTile(it + 1, a2, b2);   // prefetch: latency hides under MFMA

        #pragma unroll
        for (int ks = 0; ks < BK; ks += 32) {
            short8 af[2], bf_[2];
            #pragma unroll
            for (int mi = 0; mi < 2; ++mi)
                af[mi] = *(const short8*)&As[(wr * 32 + mi * 16 + lr) * LDP + ks + lk];
            #pragma unroll
            for (int ni = 0; ni < 2; ++ni)
                bf_[ni] = *(const short8*)&Bs[(wc * 32 + ni * 16 + lr) * LDP + ks + lk];
            #pragma unroll
            for (int mi = 0; mi < 2; ++mi)
                #pragma unroll
                for (int ni = 0; ni < 2; ++ni)
                    acc[mi][ni] = __builtin_amdgcn_mfma_f32_16x16x32_bf16(
                        af[mi], bf_[ni], acc[mi][ni], 0, 0, 0);
        }
        __syncthreads();
        if (it + 1 < NT) {
            writeTile(a2, b2);
            __syncthreads();
        }
    }

    // ---- epilogue
    #pragma unroll
    for (int mi = 0; mi < 2; ++mi) {
        #pragma unroll
        for (int ni = 0; ni < 2; ++ni) {
            int mloc = m0 + wc * 32 + ni * 16 + lr;
            float bias = convb[mloc];
            #pragma unroll
            for (int j = 0; j < 4; ++j) {
                int nloc = n0 + wr * 32 + mi * 16 + (lane >> 4) * 4 + j;
                float c = acc[mi][ni][j] + bias;
                float hv = tanhf(c) + natR[(size_t)nloc * NATSTRIDE + mloc];
                if (final_step) {
                    float res = tanhf(tanhf(hv) + x[(size_t)nloc * M_ + mloc]);
                    resOut[(size_t)nloc * M_ + mloc] = res;
                } else {
                    hOut[(size_t)nloc * M_ + mloc] = f2bf(hv);
                }
            }
        }
    }
}

// out[n][j] = conv2b + sum_k res[n][j+k] * conv2W[k]
__global__ __launch_bounds__(256) void conv_out_kernel(
    const float* __restrict__ res, const float* __restrict__ w2,
    const float* __restrict__ b2, float* __restrict__ out)
{
    __shared__ float row[M_];
    __shared__ float wk[CONVK];
    int n = blockIdx.x;
    int tid = threadIdx.x;
    for (int i = tid; i < M_; i += 256) row[i] = res[(size_t)n * M_ + i];
    if (tid < CONVK) wk[tid] = w2[tid];
    __syncthreads();
    float b = b2[0];
    int j0 = tid * 4;
    float s0 = b, s1 = b, s2 = b, s3 = b;
    float r0 = row[j0], r1 = row[j0 + 1], r2 = row[j0 + 2], r3 = row[j0 + 3];
    for (int k = 0; k < CONVK; ++k) {
        float wv = wk[k];
        s0 += r0 * wv; s1 += r1 * wv; s2 += r2 * wv; s3 += r3 * wv;
        if (k < CONVK - 1) { r0 = r1; r1 = r2; r2 = r3; r3 = row[j0 + 4 + k]; }
    }
    float* o = out + (size_t)n * OUTW + j0;
    o[0] = s0; o[1] = s1; o[2] = s2; o[3] = s3;
}

extern "C" void kernel_launch(void* const* d_in, const int* in_sizes, int n_in,
                              void* d_out, int out_size, void* d_ws, size_t ws_size,
                              hipStream_t stream) {
    const float* NATree = (const float*)d_in[0];
    const float* x      = (const float*)d_in[1];
    const float* convW  = (const float*)d_in[2];
    const float* convb  = (const float*)d_in[3];
    const float* conv2W = (const float*)d_in[4];
    const float* conv2b = (const float*)d_in[5];
    float* out = (float*)d_out;

    char* ws = (char*)d_ws;
    size_t off = 0;
    unsigned short* wcat = (unsigned short*)(ws + off);
    off += (size_t)M_ * K2_ * 2;  off = (off + 255) & ~(size_t)255;
    unsigned short* hA = (unsigned short*)(ws + off);
    off += (size_t)N_ * M_ * 2;   off = (off + 255) & ~(size_t)255;
    unsigned short* hB = (unsigned short*)(ws + off);
    off += (size_t)N_ * M_ * 2;   off = (off + 255) & ~(size_t)255;
    float* res = (float*)(ws + off);

    build_wcat<<<(M_ * K2_ + 255) / 256, 256, 0, stream>>>(convW, wcat);
    build_h0<<<(N_ * M_ + 255) / 256, 256, 0, stream>>>(NATree, hA);

    const unsigned short* hin = hA;
    unsigned short* hout = hB;
    for (int t = 0; t < 31; ++t) {
        int lrow = 30 - t;                 // r_t = NATree[:, L-2-t, :]
        int fin = (t == 30) ? 1 : 0;
        step_kernel<<<dim3(18, 16), 256, 0, stream>>>(
            NATree + (size_t)lrow * M_, hin, wcat, convb, x, hout, res, fin);
        unsigned short* tmp = hout;
        hout = (unsigned short*)hin;
        hin = tmp;
    }

    conv_out_kernel<<<1024, 256, 0, stream>>>(res, conv2W, conv2b, out);
}

// Round 3
// 897.061 us; speedup vs baseline: 3.5532x; 1.3661x over previous
//
#include <hip/hip_runtime.h>
#include <hip/hip_bf16.h>

#define N_ 1024
#define M_ 1152
#define L_ 32
#define NATSTRIDE (L_*M_)   // 36864
#define CONVK 129
#define OUTW 1024
#define NSTEP 31

#define BM 64
#define BN 64
#define BK 64
#define NT (M_ / BK)        // 18 K-tiles (K = 1152)
#define LDP 72              // padded LDS k-stride: 144B rows -> ~2-way (free) on b128

typedef __attribute__((ext_vector_type(8))) short short8;
typedef __attribute__((ext_vector_type(4))) float f32x4;

__device__ __forceinline__ unsigned short f2bf(float f) {
    unsigned int u = __float_as_uint(f);
    u += 0x7FFFu + ((u >> 16) & 1u);   // round-to-nearest-even
    return (unsigned short)(u >> 16);
}
__device__ __forceinline__ float bf2f(unsigned short b) {
    return __uint_as_float(((unsigned int)b) << 16);
}

// Split convW[m][k][2] -> w0t[m][k], w1t[m][k] (bf16, k-contiguous = B^T layout)
__global__ __launch_bounds__(256) void build_wsplit(const float* __restrict__ convW,
                                                    unsigned short* __restrict__ w0t,
                                                    unsigned short* __restrict__ w1t) {
    int idx = blockIdx.x * blockDim.x + threadIdx.x;
    if (idx >= M_ * M_) return;
    int m = idx / M_;
    int k = idx - m * M_;
    const float* s = convW + (size_t)m * (2 * M_) + 2 * k;
    w0t[idx] = f2bf(s[0]);
    w1t[idx] = f2bf(s[1]);
}

// h0 = bf16(NATree[:, L-1, :])
__global__ __launch_bounds__(256) void build_h0(const float* __restrict__ nat,
                                                unsigned short* __restrict__ h0) {
    int idx = blockIdx.x * blockDim.x + threadIdx.x;
    if (idx >= N_ * M_) return;
    int n = idx / M_;
    int m = idx - n * M_;
    h0[idx] = f2bf(nat[(size_t)n * NATSTRIDE + (size_t)(L_ - 1) * M_ + m]);
}

// Phase 1: Rpre[t*1024+n][m] = bf16( r_t[n] @ W0^T[m] + convb[m] ),  r_t = NATree[:,30-t,:]
// M = 31744 rows; grid (18, 496); 64x64 tile, dbuf LDS, 1 barrier / K-tile.
__global__ __launch_bounds__(256) void rpre_gemm(
    const float* __restrict__ nat,
    const unsigned short* __restrict__ w0t,
    const float* __restrict__ convb,
    unsigned short* __restrict__ rpre)
{
    __shared__ __align__(16) unsigned short As[2][BM * LDP];
    __shared__ __align__(16) unsigned short Bs[2][BN * LDP];

    int tid = threadIdx.x;
    int lane = tid & 63;
    int w = tid >> 6;
    int wr = w >> 1, wc = w & 1;
    int n0 = blockIdx.y * BM;          // global output row base (t*1024 + n)
    int m0 = blockIdx.x * BN;
    int t = n0 >> 10;                  // 64 | 1024 -> uniform per block
    int l = (NSTEP - 1) - t;           // NATree level for r_t
    int nbase = n0 & 1023;
    const float* natR = nat + (size_t)l * M_;

    int lr = lane & 15;
    int lk = (lane >> 4) * 8;
    int srow = tid >> 3;
    int skcol = (tid & 7) * 8;

    f32x4 acc[2][2] = {};

    auto loadTile = [&](int it, short8 a[2], short8 b[2]) {
        int kb = it * BK;
        #pragma unroll
        for (int i = 0; i < 2; ++i) {
            int row = srow + i * 32;
            const float* s = natR + (size_t)(nbase + row) * NATSTRIDE + kb + skcol;
            f32x4 v0 = *(const f32x4*)(s);
            f32x4 v1 = *(const f32x4*)(s + 4);
            short8 tt;
            #pragma unroll
            for (int e = 0; e < 4; ++e) {
                tt[e]     = (short)f2bf(v0[e]);
                tt[4 + e] = (short)f2bf(v1[e]);
            }
            a[i] = tt;
            b[i] = *(const short8*)(w0t + (size_t)(m0 + row) * M_ + kb + skcol);
        }
    };

    {
        short8 a0[2], b0[2];
        loadTile(0, a0, b0);
        #pragma unroll
        for (int i = 0; i < 2; ++i) {
            *(short8*)&As[0][(srow + i * 32) * LDP + skcol] = a0[i];
            *(short8*)&Bs[0][(srow + i * 32) * LDP + skcol] = b0[i];
        }
    }
    __syncthreads();

    int cur = 0;
    for (int it = 0; it < NT; ++it) {
        short8 a2[2], b2[2];
        if (it + 1 < NT) loadTile(it + 1, a2, b2);

        #pragma unroll
        for (int ks = 0; ks < BK; ks += 32) {
            short8 af[2], bf_[2];
            #pragma unroll
            for (int mi = 0; mi < 2; ++mi)
                af[mi] = *(const short8*)&As[cur][(wr * 32 + mi * 16 + lr) * LDP + ks + lk];
            #pragma unroll
            for (int ni = 0; ni < 2; ++ni)
                bf_[ni] = *(const short8*)&Bs[cur][(wc * 32 + ni * 16 + lr) * LDP + ks + lk];
            #pragma unroll
            for (int mi = 0; mi < 2; ++mi)
                #pragma unroll
                for (int ni = 0; ni < 2; ++ni)
                    acc[mi][ni] = __builtin_amdgcn_mfma_f32_16x16x32_bf16(
                        af[mi], bf_[ni], acc[mi][ni], 0, 0, 0);
        }
        if (it + 1 < NT) {
            #pragma unroll
            for (int i = 0; i < 2; ++i) {
                *(short8*)&As[cur ^ 1][(srow + i * 32) * LDP + skcol] = a2[i];
                *(short8*)&Bs[cur ^ 1][(srow + i * 32) * LDP + skcol] = b2[i];
            }
            __syncthreads();
            cur ^= 1;
        }
    }

    #pragma unroll
    for (int mi = 0; mi < 2; ++mi) {
        #pragma unroll
        for (int ni = 0; ni < 2; ++ni) {
            int mloc = m0 + wc * 32 + ni * 16 + lr;
            float bias = convb[mloc];
            #pragma unroll
            for (int j = 0; j < 4; ++j) {
                int g = n0 + wr * 32 + mi * 16 + (lane >> 4) * 4 + j;
                rpre[(size_t)g * M_ + mloc] = f2bf(acc[mi][ni][j] + bias);
            }
        }
    }
}

// Phase 3 (x31): C = h@W1^T; hv = tanh(C + Rpre_t) + r_t; final: res = tanh(tanh(hv)+x)
__global__ __launch_bounds__(256) void step_kernel(
    const unsigned short* __restrict__ hIn,
    const unsigned short* __restrict__ w1t,
    const unsigned short* __restrict__ rpre_t,
    const float* __restrict__ natR,          // fp32 r_t rows, stride NATSTRIDE
    const float* __restrict__ x,
    unsigned short* __restrict__ hOut,
    float* __restrict__ resOut,
    int final_step)
{
    __shared__ __align__(16) unsigned short As[2][BM * LDP];
    __shared__ __align__(16) unsigned short Bs[2][BN * LDP];

    int tid = threadIdx.x;
    int lane = tid & 63;
    int w = tid >> 6;
    int wr = w >> 1, wc = w & 1;
    int bid = blockIdx.y * 18 + blockIdx.x;
    int swz = (bid & 7) * 36 + (bid >> 3);   // 288 % 8 == 0 -> bijective XCD swizzle
    int bx = swz % 18, by = swz / 18;
    int n0 = by * BM;
    int m0 = bx * BN;
    int lr = lane & 15;
    int lk = (lane >> 4) * 8;
    int srow = tid >> 3;
    int skcol = (tid & 7) * 8;

    f32x4 acc[2][2] = {};

    auto loadTile = [&](int it, short8 a[2], short8 b[2]) {
        int kb = it * BK;
        #pragma unroll
        for (int i = 0; i < 2; ++i) {
            int row = srow + i * 32;
            a[i] = *(const short8*)(hIn + (size_t)(n0 + row) * M_ + kb + skcol);
            b[i] = *(const short8*)(w1t + (size_t)(m0 + row) * M_ + kb + skcol);
        }
    };

    {
        short8 a0[2], b0[2];
        loadTile(0, a0, b0);
        #pragma unroll
        for (int i = 0; i < 2; ++i) {
            *(short8*)&As[0][(srow + i * 32) * LDP + skcol] = a0[i];
            *(short8*)&Bs[0][(srow + i * 32) * LDP + skcol] = b0[i];
        }
    }
    __syncthreads();

    int cur = 0;
    for (int it = 0; it < NT; ++it) {
        short8 a2[2], b2[2];
        if (it + 1 < NT) loadTile(it + 1, a2, b2);

        #pragma unroll
        for (int ks = 0; ks < BK; ks += 32) {
            short8 af[2], bf_[2];
            #pragma unroll
            for (int mi = 0; mi < 2; ++mi)
                af[mi] = *(const short8*)&As[cur][(wr * 32 + mi * 16 + lr) * LDP + ks + lk];
            #pragma unroll
            for (int ni = 0; ni < 2; ++ni)
                bf_[ni] = *(const short8*)&Bs[cur][(wc * 32 + ni * 16 + lr) * LDP + ks + lk];
            #pragma unroll
            for (int mi = 0; mi < 2; ++mi)
                #pragma unroll
                for (int ni = 0; ni < 2; ++ni)
                    acc[mi][ni] = __builtin_amdgcn_mfma_f32_16x16x32_bf16(
                        af[mi], bf_[ni], acc[mi][ni], 0, 0, 0);
        }
        if (it + 1 < NT) {
            #pragma unroll
            for (int i = 0; i < 2; ++i) {
                *(short8*)&As[cur ^ 1][(srow + i * 32) * LDP + skcol] = a2[i];
                *(short8*)&Bs[cur ^ 1][(srow + i * 32) * LDP + skcol] = b2[i];
            }
            __syncthreads();
            cur ^= 1;
        }
    }

    #pragma unroll
    for (int mi = 0; mi < 2; ++mi) {
        #pragma unroll
        for (int ni = 0; ni < 2; ++ni) {
            int mloc = m0 + wc * 32 + ni * 16 + lr;
            #pragma unroll
            for (int j = 0; j < 4; ++j) {
                int nloc = n0 + wr * 32 + mi * 16 + (lane >> 4) * 4 + j;
                float pre = acc[mi][ni][j] + bf2f(rpre_t[(size_t)nloc * M_ + mloc]);
                float hv = tanhf(pre) + natR[(size_t)nloc * NATSTRIDE + mloc];
                if (final_step) {
                    float res = tanhf(tanhf(hv) + x[(size_t)nloc * M_ + mloc]);
                    resOut[(size_t)nloc * M_ + mloc] = res;
                } else {
                    hOut[(size_t)nloc * M_ + mloc] = f2bf(hv);
                }
            }
        }
    }
}

// out[n][j] = conv2b + sum_k res[n][j+k] * conv2W[k]
__global__ __launch_bounds__(256) void conv_out_kernel(
    const float* __restrict__ res, const float* __restrict__ w2,
    const float* __restrict__ b2, float* __restrict__ out)
{
    __shared__ float row[M_];
    __shared__ float wk[CONVK];
    int n = blockIdx.x;
    int tid = threadIdx.x;
    for (int i = tid; i < M_; i += 256) row[i] = res[(size_t)n * M_ + i];
    if (tid < CONVK) wk[tid] = w2[tid];
    __syncthreads();
    float b = b2[0];
    int j0 = tid * 4;
    float s0 = b, s1 = b, s2 = b, s3 = b;
    float r0 = row[j0], r1 = row[j0 + 1], r2 = row[j0 + 2], r3 = row[j0 + 3];
    for (int k = 0; k < CONVK; ++k) {
        float wv = wk[k];
        s0 += r0 * wv; s1 += r1 * wv; s2 += r2 * wv; s3 += r3 * wv;
        if (k < CONVK - 1) { r0 = r1; r1 = r2; r2 = r3; r3 = row[j0 + 4 + k]; }
    }
    float* o = out + (size_t)n * OUTW + j0;
    o[0] = s0; o[1] = s1; o[2] = s2; o[3] = s3;
}

extern "C" void kernel_launch(void* const* d_in, const int* in_sizes, int n_in,
                              void* d_out, int out_size, void* d_ws, size_t ws_size,
                              hipStream_t stream) {
    const float* NATree = (const float*)d_in[0];
    const float* x      = (const float*)d_in[1];
    const float* convW  = (const float*)d_in[2];
    const float* convb  = (const float*)d_in[3];
    const float* conv2W = (const float*)d_in[4];
    const float* conv2b = (const float*)d_in[5];
    float* out = (float*)d_out;

    char* ws = (char*)d_ws;
    size_t off = 0;
    auto alloc = [&](size_t bytes) {
        void* p = ws + off;
        off = (off + bytes + 255) & ~(size_t)255;
        return p;
    };
    unsigned short* w0t  = (unsigned short*)alloc((size_t)M_ * M_ * 2);
    unsigned short* w1t  = (unsigned short*)alloc((size_t)M_ * M_ * 2);
    unsigned short* hA   = (unsigned short*)alloc((size_t)N_ * M_ * 2);
    unsigned short* hB   = (unsigned short*)alloc((size_t)N_ * M_ * 2);
    unsigned short* rpre = (unsigned short*)alloc((size_t)NSTEP * N_ * M_ * 2);
    float*          res  = (float*)alloc((size_t)N_ * M_ * 4);

    build_wsplit<<<(M_ * M_ + 255) / 256, 256, 0, stream>>>(convW, w0t, w1t);
    build_h0<<<(N_ * M_ + 255) / 256, 256, 0, stream>>>(NATree, hA);

    // Phase 1: all 31 r_t @ W0^T + b in one GEMM (M = 31744)
    rpre_gemm<<<dim3(M_ / BN, (NSTEP * N_) / BM), 256, 0, stream>>>(NATree, w0t, convb, rpre);

    // Phase 3: sequential h-chain
    const unsigned short* hin = hA;
    unsigned short* hout = hB;
    for (int t = 0; t < NSTEP; ++t) {
        int l = (NSTEP - 1) - t;           // r_t = NATree[:, 30-t, :]
        int fin = (t == NSTEP - 1) ? 1 : 0;
        step_kernel<<<dim3(M_ / BN, N_ / BM), 256, 0, stream>>>(
            hin, w1t, rpre + (size_t)t * N_ * M_,
            NATree + (size_t)l * M_, x, hout, res, fin);
        unsigned short* tmp = hout;
        hout = (unsigned short*)hin;
        hin = tmp;
    }

    conv_out_kernel<<<1024, 256, 0, stream>>>(res, conv2W, conv2b, out);
}

// Round 4
// 754.325 us; speedup vs baseline: 4.2256x; 1.1892x over previous
//
#include <hip/hip_runtime.h>
#include <hip/hip_bf16.h>

#define N_ 1024
#define M_ 1152
#define L_ 32
#define NATSTRIDE (L_*M_)   // 36864
#define CONVK 129
#define OUTW 1024
#define NSTEP 31

typedef __attribute__((ext_vector_type(8))) short short8;
typedef __attribute__((ext_vector_type(4))) float f32x4;

__device__ __forceinline__ unsigned short f2bf(float f) {
    unsigned int u = __float_as_uint(f);
    u += 0x7FFFu + ((u >> 16) & 1u);   // round-to-nearest-even
    return (unsigned short)(u >> 16);
}
__device__ __forceinline__ float bf2f(unsigned short b) {
    return __uint_as_float(((unsigned int)b) << 16);
}

// Split convW[m][k][2] -> w0t[m][k], w1t[m][k] (bf16, k-contiguous = B^T layout)
__global__ __launch_bounds__(256) void build_wsplit(const float* __restrict__ convW,
                                                    unsigned short* __restrict__ w0t,
                                                    unsigned short* __restrict__ w1t) {
    int idx = blockIdx.x * blockDim.x + threadIdx.x;
    if (idx >= M_ * M_) return;
    int m = idx / M_;
    int k = idx - m * M_;
    const float* s = convW + (size_t)m * (2 * M_) + 2 * k;
    w0t[idx] = f2bf(s[0]);
    w1t[idx] = f2bf(s[1]);
}

// h0 = bf16(NATree[:, L-1, :])
__global__ __launch_bounds__(256) void build_h0(const float* __restrict__ nat,
                                                unsigned short* __restrict__ h0) {
    int idx = blockIdx.x * blockDim.x + threadIdx.x;
    if (idx >= N_ * M_) return;
    int n = idx / M_;
    int m = idx - n * M_;
    h0[idx] = f2bf(nat[(size_t)n * NATSTRIDE + (size_t)(L_ - 1) * M_ + m]);
}

// ---------------- Phase 1: Rpre = bf16( r_t @ W0^T + b ) for all t ----------------
// M = 31744 output rows (t*1024+n), 128x128 tile, 4 waves (2x2 of 64x64), BK=64 dbuf.
#define P_BM 128
#define P_BN 128
#define P_BK 64
#define P_NT (M_ / P_BK)    // 18
#define P_LDP 72

__global__ __launch_bounds__(256) void rpre_gemm(
    const float* __restrict__ nat,
    const unsigned short* __restrict__ w0t,
    const float* __restrict__ convb,
    unsigned short* __restrict__ rpre)
{
    __shared__ __align__(16) unsigned short As[2][P_BM * P_LDP];
    __shared__ __align__(16) unsigned short Bs[2][P_BN * P_LDP];

    int tid = threadIdx.x;
    int lane = tid & 63;
    int w = tid >> 6;
    int wr = w >> 1, wc = w & 1;           // 2x2 waves, 64x64 each
    // chunked XCD swizzle: 2232 blocks = 8 * 279; XCD k gets 31 contiguous panel-rows
    int raw = blockIdx.y * 9 + blockIdx.x;
    int logical = (raw & 7) * 279 + (raw >> 3);
    int bx = logical % 9, by = logical / 9;
    int n0 = by * P_BM;                    // row in [0, 31744)
    int m0 = bx * P_BN;
    int t = n0 >> 10;                      // 128 | 1024 -> uniform per block
    int l = (NSTEP - 1) - t;
    int nbase = n0 & 1023;
    const float* natR = nat + (size_t)l * M_;

    int lr = lane & 15;
    int lk = (lane >> 4) * 8;
    int srow = tid >> 3;                   // 32 rows per pass, 4 passes
    int skcol = (tid & 7) * 8;

    f32x4 acc[4][4] = {};

    auto loadTile = [&](int it, short8 a[4], short8 b[4]) {
        int kb = it * P_BK;
        #pragma unroll
        for (int i = 0; i < 4; ++i) {
            int row = srow + i * 32;
            const float* s = natR + (size_t)(nbase + row) * NATSTRIDE + kb + skcol;
            f32x4 v0 = *(const f32x4*)(s);
            f32x4 v1 = *(const f32x4*)(s + 4);
            short8 tt;
            #pragma unroll
            for (int e = 0; e < 4; ++e) {
                tt[e]     = (short)f2bf(v0[e]);
                tt[4 + e] = (short)f2bf(v1[e]);
            }
            a[i] = tt;
            b[i] = *(const short8*)(w0t + (size_t)(m0 + row) * M_ + kb + skcol);
        }
    };
    auto writeTile = [&](int buf, short8 a[4], short8 b[4]) {
        #pragma unroll
        for (int i = 0; i < 4; ++i) {
            *(short8*)&As[buf][(srow + i * 32) * P_LDP + skcol] = a[i];
            *(short8*)&Bs[buf][(srow + i * 32) * P_LDP + skcol] = b[i];
        }
    };

    {
        short8 a0[4], b0[4];
        loadTile(0, a0, b0);
        writeTile(0, a0, b0);
    }
    __syncthreads();

    int cur = 0;
    for (int it = 0; it < P_NT; ++it) {
        short8 a2[4], b2[4];
        if (it + 1 < P_NT) loadTile(it + 1, a2, b2);

        #pragma unroll
        for (int ks = 0; ks < P_BK; ks += 32) {
            short8 af[4], bf_[4];
            #pragma unroll
            for (int mi = 0; mi < 4; ++mi)
                af[mi] = *(const short8*)&As[cur][(wr * 64 + mi * 16 + lr) * P_LDP + ks + lk];
            #pragma unroll
            for (int ni = 0; ni < 4; ++ni)
                bf_[ni] = *(const short8*)&Bs[cur][(wc * 64 + ni * 16 + lr) * P_LDP + ks + lk];
            #pragma unroll
            for (int mi = 0; mi < 4; ++mi)
                #pragma unroll
                for (int ni = 0; ni < 4; ++ni)
                    acc[mi][ni] = __builtin_amdgcn_mfma_f32_16x16x32_bf16(
                        af[mi], bf_[ni], acc[mi][ni], 0, 0, 0);
        }
        if (it + 1 < P_NT) {
            writeTile(cur ^ 1, a2, b2);
            __syncthreads();
            cur ^= 1;
        }
    }

    #pragma unroll
    for (int mi = 0; mi < 4; ++mi) {
        #pragma unroll
        for (int ni = 0; ni < 4; ++ni) {
            int mloc = m0 + wc * 64 + ni * 16 + lr;
            float bias = convb[mloc];
            #pragma unroll
            for (int j = 0; j < 4; ++j) {
                int g = n0 + wr * 64 + mi * 16 + (lane >> 4) * 4 + j;
                rpre[(size_t)g * M_ + mloc] = f2bf(acc[mi][ni][j] + bias);
            }
        }
    }
}

// ---------------- Phase 3 (x31): C = h@W1^T; hv = tanh(C + Rpre_t) + r_t ----------------
// 64x64 tile, 4 waves (2x2 of 32x32), BK=128 (9 K-iters), dbuf.
#define S_BM 64
#define S_BN 64
#define S_BK 128
#define S_NT (M_ / S_BK)    // 9
#define S_LDP 136

__global__ __launch_bounds__(256) void step_kernel(
    const unsigned short* __restrict__ hIn,
    const unsigned short* __restrict__ w1t,
    const unsigned short* __restrict__ rpre_t,
    const float* __restrict__ natR,          // fp32 r_t rows, stride NATSTRIDE
    const float* __restrict__ x,
    unsigned short* __restrict__ hOut,
    float* __restrict__ resOut,
    int final_step)
{
    __shared__ __align__(16) unsigned short As[2][S_BM * S_LDP];
    __shared__ __align__(16) unsigned short Bs[2][S_BN * S_LDP];

    int tid = threadIdx.x;
    int lane = tid & 63;
    int w = tid >> 6;
    int wr = w >> 1, wc = w & 1;
    int bid = blockIdx.y * 18 + blockIdx.x;
    int swz = (bid & 7) * 36 + (bid >> 3);   // 288 % 8 == 0 -> bijective XCD swizzle
    int bx = swz % 18, by = swz / 18;
    int n0 = by * S_BM;
    int m0 = bx * S_BN;
    int lr = lane & 15;
    int lk = (lane >> 4) * 8;
    int srow = tid >> 4;                     // 16 rows per pass, 4 passes
    int skcol = (tid & 15) * 8;

    f32x4 acc[2][2] = {};

    auto loadTile = [&](int it, short8 a[4], short8 b[4]) {
        int kb = it * S_BK;
        #pragma unroll
        for (int i = 0; i < 4; ++i) {
            int row = srow + i * 16;
            a[i] = *(const short8*)(hIn + (size_t)(n0 + row) * M_ + kb + skcol);
            b[i] = *(const short8*)(w1t + (size_t)(m0 + row) * M_ + kb + skcol);
        }
    };
    auto writeTile = [&](int buf, short8 a[4], short8 b[4]) {
        #pragma unroll
        for (int i = 0; i < 4; ++i) {
            *(short8*)&As[buf][(srow + i * 16) * S_LDP + skcol] = a[i];
            *(short8*)&Bs[buf][(srow + i * 16) * S_LDP + skcol] = b[i];
        }
    };

    {
        short8 a0[4], b0[4];
        loadTile(0, a0, b0);
        writeTile(0, a0, b0);
    }
    __syncthreads();

    int cur = 0;
    for (int it = 0; it < S_NT; ++it) {
        short8 a2[4], b2[4];
        if (it + 1 < S_NT) loadTile(it + 1, a2, b2);

        #pragma unroll
        for (int ks = 0; ks < S_BK; ks += 32) {
            short8 af[2], bf_[2];
            #pragma unroll
            for (int mi = 0; mi < 2; ++mi)
                af[mi] = *(const short8*)&As[cur][(wr * 32 + mi * 16 + lr) * S_LDP + ks + lk];
            #pragma unroll
            for (int ni = 0; ni < 2; ++ni)
                bf_[ni] = *(const short8*)&Bs[cur][(wc * 32 + ni * 16 + lr) * S_LDP + ks + lk];
            #pragma unroll
            for (int mi = 0; mi < 2; ++mi)
                #pragma unroll
                for (int ni = 0; ni < 2; ++ni)
                    acc[mi][ni] = __builtin_amdgcn_mfma_f32_16x16x32_bf16(
                        af[mi], bf_[ni], acc[mi][ni], 0, 0, 0);
        }
        if (it + 1 < S_NT) {
            writeTile(cur ^ 1, a2, b2);
            __syncthreads();
            cur ^= 1;
        }
    }

    #pragma unroll
    for (int mi = 0; mi < 2; ++mi) {
        #pragma unroll
        for (int ni = 0; ni < 2; ++ni) {
            int mloc = m0 + wc * 32 + ni * 16 + lr;
            #pragma unroll
            for (int j = 0; j < 4; ++j) {
                int nloc = n0 + wr * 32 + mi * 16 + (lane >> 4) * 4 + j;
                float pre = acc[mi][ni][j] + bf2f(rpre_t[(size_t)nloc * M_ + mloc]);
                float hv = tanhf(pre) + natR[(size_t)nloc * NATSTRIDE + mloc];
                if (final_step) {
                    float res = tanhf(tanhf(hv) + x[(size_t)nloc * M_ + mloc]);
                    resOut[(size_t)nloc * M_ + mloc] = res;
                } else {
                    hOut[(size_t)nloc * M_ + mloc] = f2bf(hv);
                }
            }
        }
    }
}

// out[n][j] = conv2b + sum_k res[n][j+k] * conv2W[k]
__global__ __launch_bounds__(256) void conv_out_kernel(
    const float* __restrict__ res, const float* __restrict__ w2,
    const float* __restrict__ b2, float* __restrict__ out)
{
    __shared__ float row[M_];
    __shared__ float wk[CONVK];
    int n = blockIdx.x;
    int tid = threadIdx.x;
    for (int i = tid; i < M_; i += 256) row[i] = res[(size_t)n * M_ + i];
    if (tid < CONVK) wk[tid] = w2[tid];
    __syncthreads();
    float b = b2[0];
    int j0 = tid * 4;
    float s0 = b, s1 = b, s2 = b, s3 = b;
    float r0 = row[j0], r1 = row[j0 + 1], r2 = row[j0 + 2], r3 = row[j0 + 3];
    for (int k = 0; k < CONVK; ++k) {
        float wv = wk[k];
        s0 += r0 * wv; s1 += r1 * wv; s2 += r2 * wv; s3 += r3 * wv;
        if (k < CONVK - 1) { r0 = r1; r1 = r2; r2 = r3; r3 = row[j0 + 4 + k]; }
    }
    float* o = out + (size_t)n * OUTW + j0;
    o[0] = s0; o[1] = s1; o[2] = s2; o[3] = s3;
}

extern "C" void kernel_launch(void* const* d_in, const int* in_sizes, int n_in,
                              void* d_out, int out_size, void* d_ws, size_t ws_size,
                              hipStream_t stream) {
    const float* NATree = (const float*)d_in[0];
    const float* x      = (const float*)d_in[1];
    const float* convW  = (const float*)d_in[2];
    const float* convb  = (const float*)d_in[3];
    const float* conv2W = (const float*)d_in[4];
    const float* conv2b = (const float*)d_in[5];
    float* out = (float*)d_out;

    char* ws = (char*)d_ws;
    size_t off = 0;
    auto alloc = [&](size_t bytes) {
        void* p = ws + off;
        off = (off + bytes + 255) & ~(size_t)255;
        return p;
    };
    unsigned short* w0t  = (unsigned short*)alloc((size_t)M_ * M_ * 2);
    unsigned short* w1t  = (unsigned short*)alloc((size_t)M_ * M_ * 2);
    unsigned short* hA   = (unsigned short*)alloc((size_t)N_ * M_ * 2);
    unsigned short* hB   = (unsigned short*)alloc((size_t)N_ * M_ * 2);
    unsigned short* rpre = (unsigned short*)alloc((size_t)NSTEP * N_ * M_ * 2);
    float*          res  = (float*)alloc((size_t)N_ * M_ * 4);

    build_wsplit<<<(M_ * M_ + 255) / 256, 256, 0, stream>>>(convW, w0t, w1t);
    build_h0<<<(N_ * M_ + 255) / 256, 256, 0, stream>>>(NATree, hA);

    // Phase 1: all 31 r_t @ W0^T + b in one GEMM (M = 31744), 128x128 tiles
    rpre_gemm<<<dim3(M_ / P_BN, (NSTEP * N_) / P_BM), 256, 0, stream>>>(NATree, w0t, convb, rpre);

    // Phase 3: sequential h-chain
    const unsigned short* hin = hA;
    unsigned short* hout = hB;
    for (int t = 0; t < NSTEP; ++t) {
        int l = (NSTEP - 1) - t;           // r_t = NATree[:, 30-t, :]
        int fin = (t == NSTEP - 1) ? 1 : 0;
        step_kernel<<<dim3(M_ / S_BN, N_ / S_BM), 256, 0, stream>>>(
            hin, w1t, rpre + (size_t)t * N_ * M_,
            NATree + (size_t)l * M_, x, hout, res, fin);
        unsigned short* tmp = hout;
        hout = (unsigned short*)hin;
        hin = tmp;
    }

    conv_out_kernel<<<1024, 256, 0, stream>>>(res, conv2W, conv2b, out);
}